// Round 4
// baseline (386.284 us; speedup 1.0000x reference)
//
#include <hip/hip_runtime.h>
#include <stdint.h>

typedef __attribute__((ext_vector_type(8))) short short8;   // 8 x bf16 MFMA operand
typedef __attribute__((ext_vector_type(4))) float floatx4;  // MFMA accumulator

#define DEV __device__ __forceinline__

DEV unsigned short f2bf(float x) {  // fp32 -> bf16 RNE (epilogue-only)
  unsigned u = __float_as_uint(x);
  u += 0x7fffu + ((u >> 16) & 1u);
  return (unsigned short)(u >> 16);
}

// pack two fp32 -> two bf16 (round-half-up) in 3 VALU: 2 adds + v_perm
DEV unsigned pkbf(float hi, float lo) {
  return __builtin_amdgcn_perm(__float_as_uint(hi) + 0x8000u,
                               __float_as_uint(lo) + 0x8000u, 0x07060302u);
}

// single-instruction pack: dst = {lo16: bf16(a), hi16: bf16(b)} (RNE)
DEV unsigned cvtpk(float a, float b) {
  unsigned r;
  asm("v_cvt_pk_bf16_f32 %0, %1, %2" : "=v"(r) : "v"(a), "v"(b));
  return r;
}

DEV void load_lds16(const unsigned short* g, unsigned short* l) {
  __builtin_amdgcn_global_load_lds(
      (const __attribute__((address_space(1))) void*)g,
      (__attribute__((address_space(3))) void*)l, 16, 0, 0);
}

DEV void lds_fence() { asm volatile("" ::: "memory"); }  // wave-private LDS RAW/WAR ordering

// counted vmcnt + raw barrier (T4): never drain to 0 mid-loop
#define ASM_VMCNT(n) asm volatile("s_waitcnt vmcnt(" #n ")" ::: "memory")
DEV void sched_fence() { __builtin_amdgcn_sched_barrier(0); }

// ---------------- one-shot fp32 -> bf16 of all 7 tensors ----------------
__global__ void cvt_all(const float* __restrict__ Wq, const float* __restrict__ Wk,
                        const float* __restrict__ Wv, const float* __restrict__ Wo,
                        const float* __restrict__ Xq, const float* __restrict__ Xk,
                        const float* __restrict__ Xv,
                        unsigned short* __restrict__ Wb, unsigned short* __restrict__ XqB,
                        unsigned short* __restrict__ XkB, unsigned short* __restrict__ XvB) {
  int bid = blockIdx.x;
  const float* src;
  unsigned short* dst;
  int off;
  if (bid < 4096) {
    int sel = bid >> 10;
    src = sel == 0 ? Wq : sel == 1 ? Wk : sel == 2 ? Wv : Wo;
    dst = Wb + (size_t)sel * 1048576;
    off = bid & 1023;
  } else {
    bid -= 4096;
    int sel = bid >> 13;
    src = sel == 0 ? Xq : sel == 1 ? Xk : Xv;
    dst = sel == 0 ? XqB : sel == 1 ? XkB : XvB;
    off = bid & 8191;
  }
  int i = (off * 256 + threadIdx.x) * 4;
  float4 v = *(const float4*)(src + i);
  uint2 o;
  o.x = pkbf(v.y, v.x);
  o.y = pkbf(v.w, v.z);
  *(uint2*)(dst + i) = o;
}

// ---------------- fused QKV projection: depth-2 counted-vmcnt pipeline, grid (8,64,3) --------
// z-aware chunked XCD swizzle: flat n = x + 8y + 512z; np = 192*(n&7) + (n>>3) gives each
// XCD 192 consecutive np (d-block fastest -> its 2MB W panel reused 24x; X panels stream).
#define SCQ (0.125f * 1.44269504089f)
__global__ __launch_bounds__(256, 3) void qkv_gemm(
    const unsigned short* __restrict__ XqB, const unsigned short* __restrict__ XkB,
    const unsigned short* __restrict__ XvB,
    const unsigned short* __restrict__ Wb,
    const float* __restrict__ bq, const float* __restrict__ bk, const float* __restrict__ bv,
    unsigned short* __restrict__ Qp, unsigned short* __restrict__ Kp,
    unsigned short* __restrict__ VTp) {
  __shared__ alignas(16) unsigned short Xs[3][128 * 32];
  __shared__ alignas(16) unsigned short Ws[3][128 * 32];
  const int n = blockIdx.x + 8 * blockIdx.y + 512 * blockIdx.z;
  const int np = 192 * (n & 7) + (n >> 3);  // bijective over 1536
  const int z = np >> 9;
  const int rr = np & 511;
  const int wo = (rr & 7) * 128;   // d block (fastest -> W L2-hot)
  const int xo = (rr >> 3) * 128;  // s block
  const unsigned short* X = z == 0 ? XqB : z == 1 ? XkB : XvB;
  const unsigned short* W = Wb + (size_t)z * 1048576;
  const float* bias = z == 0 ? bq : z == 1 ? bk : bv;

  const int tid = threadIdx.x;
  const int lane = tid & 63, wave = tid >> 6;
  const int lcol = lane & 15, quad = lane >> 4;
  const int wm = (wave & 1) * 64;
  const int wn = (wave >> 1) * 64;

  floatx4 acc[4][4];
  for (int mi = 0; mi < 4; ++mi)
    for (int ni = 0; ni < 4; ++ni)
      for (int r = 0; r < 4; ++r) acc[mi][ni][r] = 0.f;

  auto stage = [&](int kt, int buf) {  // 4 vmem ops / thread / tile
    const int k0 = kt * 32;
    int c = tid;
    load_lds16(W + (size_t)(wo + (c >> 2)) * 1024 + k0 + (c & 3) * 8, Ws[buf] + c * 8);
    load_lds16(X + (size_t)(xo + (c >> 2)) * 1024 + k0 + (c & 3) * 8, Xs[buf] + c * 8);
    c = tid + 256;
    load_lds16(W + (size_t)(wo + (c >> 2)) * 1024 + k0 + (c & 3) * 8, Ws[buf] + c * 8);
    load_lds16(X + (size_t)(xo + (c >> 2)) * 1024 + k0 + (c & 3) * 8, Xs[buf] + c * 8);
  };

  stage(0, 0);
  stage(1, 1);
  int cur = 0;
  for (int kt = 0; kt < 32; ++kt) {
    sched_fence();
    ASM_VMCNT(4);                    // tile kt landed; tile kt+1 still in flight
    __builtin_amdgcn_s_barrier();    // cross-wave visibility of tile kt
    sched_fence();
    int nb = cur + 2; if (nb >= 3) nb -= 3;
    stage((kt + 2) & 31, nb);        // wrap-issue keeps vmcnt count uniform at tail
    const unsigned short* Ab = (z < 2) ? Ws[cur] : Xs[cur];  // A rows (m)
    const unsigned short* Bb = (z < 2) ? Xs[cur] : Ws[cur];  // B rows (n)
    short8 af[4], bfr[4];
#pragma unroll
    for (int mi = 0; mi < 4; ++mi)
      af[mi] = *(const short8*)(Ab + (wm + mi * 16 + lcol) * 32 + quad * 8);
#pragma unroll
    for (int ni = 0; ni < 4; ++ni)
      bfr[ni] = *(const short8*)(Bb + (wn + ni * 16 + lcol) * 32 + quad * 8);
#pragma unroll
    for (int mi = 0; mi < 4; ++mi)
#pragma unroll
      for (int ni = 0; ni < 4; ++ni)
        acc[mi][ni] = __builtin_amdgcn_mfma_f32_16x16x32_bf16(af[mi], bfr[ni], acc[mi][ni], 0, 0, 0);
    cur = (cur == 2) ? 0 : cur + 1;
  }

  if (z < 2) {  // lane: d = base+quad*4+r (consecutive), s = ...+lcol -> packed uint2
    unsigned short* Out = z == 0 ? Qp : Kp;
    const float scl = z == 0 ? SCQ : 1.f;
#pragma unroll
    for (int mi = 0; mi < 4; ++mi) {
      int dbase = wo + wm + mi * 16 + quad * 4;
      float4 bv4 = *(const float4*)(bias + dbase);
      int h = dbase >> 6, dk = dbase & 63;
#pragma unroll
      for (int ni = 0; ni < 4; ++ni) {
        int sg = xo + wn + ni * 16 + lcol;  // = b*2048 + s
        int bb = sg >> 11, ss = sg & 2047;
        uint2 o;
        o.x = pkbf((acc[mi][ni][1] + bv4.y) * scl, (acc[mi][ni][0] + bv4.x) * scl);
        o.y = pkbf((acc[mi][ni][3] + bv4.w) * scl, (acc[mi][ni][2] + bv4.z) * scl);
        *(uint2*)(Out + ((size_t)(bb * 16 + h) * 2048 + ss) * 64 + dk) = o;
      }
    }
  } else {  // lane: s = base+quad*4+r (consecutive), d = ...+lcol -> packed uint2 into V^T
#pragma unroll
    for (int ni = 0; ni < 4; ++ni) {
      int dg = wo + wn + ni * 16 + lcol;
      float bvx = bias[dg];
      int h = dg >> 6, dk = dg & 63;
#pragma unroll
      for (int mi = 0; mi < 4; ++mi) {
        int sbase = xo + wm + mi * 16 + quad * 4;
        int bb = sbase >> 11, ss = sbase & 2047;
        uint2 o;
        o.x = pkbf(acc[mi][ni][1] + bvx, acc[mi][ni][0] + bvx);
        o.y = pkbf(acc[mi][ni][3] + bvx, acc[mi][ni][2] + bvx);
        *(uint2*)(VTp + ((size_t)(bb * 16 + h) * 64 + dk) * 2048 + ss) = o;
      }
    }
  }
}

// ---------------- final O-projection: fp32 out, depth-2 counted-vmcnt ----------------
__global__ __launch_bounds__(256, 3) void gemm_o(
    const unsigned short* __restrict__ A, const unsigned short* __restrict__ Bw,
    const float* __restrict__ bias, float* __restrict__ Out) {
  __shared__ alignas(16) unsigned short Cs[3][128 * 32];
  __shared__ alignas(16) unsigned short Wos[3][128 * 32];
  const int tid = threadIdx.x;
  const int lane = tid & 63, wave = tid >> 6;
  const int lcol = lane & 15, quad = lane >> 4;
  const int n2 = blockIdx.x + 8 * blockIdx.y;  // XCD L2-locality remap (2MB Ctx + 2MB Wo)
  const int xcd = n2 & 7, ii = n2 >> 3;
  const int co = (ii >> 3) * 128;              // output-col block
  const int so = (xcd * 8 + (ii & 7)) * 128;   // s block
  const int wm = (wave & 1) * 64;
  const int wn = (wave >> 1) * 64;

  floatx4 acc[4][4];
  for (int mi = 0; mi < 4; ++mi)
    for (int ni = 0; ni < 4; ++ni)
      for (int r = 0; r < 4; ++r) acc[mi][ni][r] = 0.f;

  auto stage = [&](int kt, int buf) {
    const int k0 = kt * 32;
    int c = tid;
    load_lds16(Bw + (size_t)(co + (c >> 2)) * 1024 + k0 + (c & 3) * 8, Wos[buf] + c * 8);
    load_lds16(A  + (size_t)(so + (c >> 2)) * 1024 + k0 + (c & 3) * 8, Cs[buf] + c * 8);
    c = tid + 256;
    load_lds16(Bw + (size_t)(co + (c >> 2)) * 1024 + k0 + (c & 3) * 8, Wos[buf] + c * 8);
    load_lds16(A  + (size_t)(so + (c >> 2)) * 1024 + k0 + (c & 3) * 8, Cs[buf] + c * 8);
  };

  stage(0, 0);
  stage(1, 1);
  int cur = 0;
  for (int kt = 0; kt < 32; ++kt) {
    sched_fence();
    ASM_VMCNT(4);
    __builtin_amdgcn_s_barrier();
    sched_fence();
    int nb = cur + 2; if (nb >= 3) nb -= 3;
    stage((kt + 2) & 31, nb);
    short8 af[4], bfr[4];
#pragma unroll
    for (int mi = 0; mi < 4; ++mi)
      af[mi] = *(const short8*)(Wos[cur] + (wm + mi * 16 + lcol) * 32 + quad * 8);
#pragma unroll
    for (int ni = 0; ni < 4; ++ni)
      bfr[ni] = *(const short8*)(Cs[cur] + (wn + ni * 16 + lcol) * 32 + quad * 8);
#pragma unroll
    for (int mi = 0; mi < 4; ++mi)
#pragma unroll
      for (int ni = 0; ni < 4; ++ni)
        acc[mi][ni] = __builtin_amdgcn_mfma_f32_16x16x32_bf16(af[mi], bfr[ni], acc[mi][ni], 0, 0, 0);
    cur = (cur == 2) ? 0 : cur + 1;
  }
#pragma unroll
  for (int mi = 0; mi < 4; ++mi) {
    int cb = co + wm + mi * 16 + quad * 4;  // 4 consecutive output cols
    float4 bv4 = *(const float4*)(bias + cb);
#pragma unroll
    for (int ni = 0; ni < 4; ++ni) {
      int sg = so + wn + ni * 16 + lcol;
      float4 o;
      o.x = acc[mi][ni][0] + bv4.x;
      o.y = acc[mi][ni][1] + bv4.y;
      o.z = acc[mi][ni][2] + bv4.z;
      o.w = acc[mi][ni][3] + bv4.w;
      *(float4*)(Out + (size_t)sg * 1024 + cb) = o;
    }
  }
}

// ---------------- flash attention: one block = (b, h, 128 q rows), 2 waves x 64q ----------
// Round-4: per-wave q-tile 32->64 (2 waves of 128 threads). Same per-SIMD VALU/exp work,
// but per-CU LDS frag traffic drops ~33% (K/V frags amortize over 2x output) and barrier
// population halves. VGPR ~220 (2 waves/SIMD budget). LDS 40KB -> 4 blocks/CU.
__global__ __launch_bounds__(128, 2) void attn_kernel(
    const unsigned short* __restrict__ Qp, const unsigned short* __restrict__ Kp,
    const unsigned short* __restrict__ VTp, unsigned short* __restrict__ Ctx) {
  __shared__ alignas(16) unsigned short Ks[2][64 * 64];  // K tiles, dbuf (16KB)
  __shared__ alignas(16) unsigned short Vt[64 * 64];     // V^T tile (8KB)
  __shared__ alignas(16) unsigned short Ps[128 * 64];    // Q stage -> P -> O stage (16KB)

  const int tid = threadIdx.x;
  const int lane = tid & 63, wave = tid >> 6;
  const int lcol = lane & 15, quad = lane >> 4;
  const int wq = wave * 64;
  // XCD L2-locality remap: n = qt + 16*hb; xcd owns hb-span of 8 (4MB K+V)
  const int n = blockIdx.x + 16 * (blockIdx.y + 16 * blockIdx.z);
  const int xcd = n & 7, ii = n >> 3;
  const int hb = xcd * 8 + (ii & 7);  // = b*16 + h
  const int qt = ii >> 3;
  const size_t bh = (size_t)hb * 2048 * 64;
  const int b = hb >> 4;
  const unsigned short* Qb = Qp + bh + (size_t)qt * 128 * 64;
  const unsigned short* Kb = Kp + bh;
  const unsigned short* VTb = VTp + bh;

  // prologue: Q tile into Ps (swizzled) + K tile 0 into Ks[0]  (128 threads)
#pragma unroll
  for (int i = 0; i < 8; ++i) {
    int p = tid + i * 128;
    int row = p >> 3, pj = p & 7;
    load_lds16(Qb + row * 64 + ((pj ^ (row & 7)) * 8), Ps + p * 8);
  }
#pragma unroll
  for (int i = 0; i < 4; ++i) {
    int p = tid + i * 128;
    int kr = p >> 3, kj = p & 7;
    load_lds16(Kb + kr * 64 + ((kj ^ (kr & 7)) * 8), Ks[0] + p * 8);
  }
  __syncthreads();  // Q + K0 resident

  short8 qf[4][2];
#pragma unroll
  for (int ni = 0; ni < 4; ++ni)
#pragma unroll
    for (int ks = 0; ks < 2; ++ks) {
      int row = wq + ni * 16 + lcol;
      qf[ni][ks] = *(const short8*)(Ps + row * 64 + (((ks * 4 + quad) ^ (row & 7)) * 8));
    }

  // bf16 1.0 splat: B-operand for the L (row-sum) MFMA
  short8 ones;
#pragma unroll
  for (int j = 0; j < 8; ++j) ones[j] = (short)0x3f80;

  float M[4] = {-1e30f, -1e30f, -1e30f, -1e30f};
  floatx4 Oacc[4][4];
  floatx4 OaccL[4];  // L in C-row layout: OaccL[mi][r] = sum_k P[q=wq+mi*16+quad*4+r][k]
  for (int mi = 0; mi < 4; ++mi) {
    for (int nd = 0; nd < 4; ++nd)
      for (int r = 0; r < 4; ++r) Oacc[mi][nd][r] = 0.f;
    for (int r = 0; r < 4; ++r) OaccL[mi][r] = 0.f;
  }

  for (int jt = 0; jt < 32; ++jt) {
    const int cur = jt & 1;
    // issue V(jt) first (4 ops), then K(jt+1) (4 ops) -> vmcnt(4) waits exactly V
#pragma unroll
    for (int i = 0; i < 4; ++i) {
      int p = tid + i * 128;
      int vr = p >> 3, vj = p & 7;
      load_lds16(VTb + (size_t)vr * 2048 + jt * 64 + ((vj ^ (vr & 7)) * 8), Vt + p * 8);
    }
    const int jn = (jt + 1) & 31;  // wrap-issue at tail keeps vmcnt count uniform
#pragma unroll
    for (int i = 0; i < 4; ++i) {
      int p = tid + i * 128;
      int kr = p >> 3, kj = p & 7;
      load_lds16(Kb + (size_t)jn * 4096 + kr * 64 + ((kj ^ (kr & 7)) * 8), Ks[cur ^ 1] + p * 8);
    }

    // S^T = K @ Q^T  (Q pre-scaled: sacc already in base-2 logit units)
    const unsigned short* Kc = Ks[cur];
    floatx4 sacc[4][4];  // [mi = k-block][ni = q-block]
    for (int mi = 0; mi < 4; ++mi)
      for (int ni = 0; ni < 4; ++ni)
        for (int r = 0; r < 4; ++r) sacc[mi][ni][r] = 0.f;
#pragma unroll
    for (int mi = 0; mi < 4; ++mi) {
      int row = mi * 16 + lcol;
      int sw = (row & 7);
      short8 kf0 = *(const short8*)(Kc + row * 64 + ((quad ^ sw) * 8));
      short8 kf1 = *(const short8*)(Kc + row * 64 + (((4 + quad) ^ sw) * 8));
#pragma unroll
      for (int ni = 0; ni < 4; ++ni) {
        sacc[mi][ni] = __builtin_amdgcn_mfma_f32_16x16x32_bf16(kf0, qf[ni][0], sacc[mi][ni], 0, 0, 0);
        sacc[mi][ni] = __builtin_amdgcn_mfma_f32_16x16x32_bf16(kf1, qf[ni][1], sacc[mi][ni], 0, 0, 0);
      }
    }

    // ---- lane-local max via max3 trees ----
    float lmax[4];
#pragma unroll
    for (int ni = 0; ni < 4; ++ni) {
      float a0 = fmaxf(fmaxf(sacc[0][ni][0], sacc[0][ni][1]), sacc[0][ni][2]);
      float a1 = fmaxf(fmaxf(sacc[0][ni][3], sacc[1][ni][0]), sacc[1][ni][1]);
      float a2 = fmaxf(fmaxf(sacc[1][ni][2], sacc[1][ni][3]), sacc[2][ni][0]);
      float a3 = fmaxf(fmaxf(sacc[2][ni][1], sacc[2][ni][2]), sacc[2][ni][3]);
      float a4 = fmaxf(fmaxf(sacc[3][ni][0], sacc[3][ni][1]), sacc[3][ni][2]);
      float b0 = fmaxf(fmaxf(a0, a1), a2);
      float b1 = fmaxf(fmaxf(a3, a4), sacc[3][ni][3]);
      lmax[ni] = fmaxf(b0, b1);
    }
    // defer-max: skip the reduce+rescale when no lane's local max exceeds M+8
    const int skip = __all((lmax[0] <= M[0] + 8.f) & (lmax[1] <= M[1] + 8.f) &
                           (lmax[2] <= M[2] + 8.f) & (lmax[3] <= M[3] + 8.f));
    if (!skip) {
      float alpha[4];
#pragma unroll
      for (int ni = 0; ni < 4; ++ni) {
        float m = lmax[ni];
        m = fmaxf(m, __shfl_xor(m, 16));
        m = fmaxf(m, __shfl_xor(m, 32));
        float mnew = fmaxf(M[ni], m);
        alpha[ni] = exp2f(M[ni] - mnew);
        M[ni] = mnew;
      }
#pragma unroll
      for (int mi = 0; mi < 4; ++mi)
#pragma unroll
        for (int r = 0; r < 4; ++r) {
          float a = __shfl(alpha[mi], quad * 4 + r);
          floatx4 av = {a, a, a, a};
#pragma unroll
          for (int nd = 0; nd < 4; ++nd) Oacc[mi][nd] *= av;
          OaccL[mi][r] *= a;
        }
    }
    // exp (no sum -- L comes from the ones-column MFMA)
#pragma unroll
    for (int ni = 0; ni < 4; ++ni) {
      floatx4 mv = {M[ni], M[ni], M[ni], M[ni]};
#pragma unroll
      for (int mi = 0; mi < 4; ++mi) {
        floatx4 t = sacc[mi][ni] - mv;
        sacc[mi][ni][0] = exp2f(t[0]);
        sacc[mi][ni][1] = exp2f(t[1]);
        sacc[mi][ni][2] = exp2f(t[2]);
        sacc[mi][ni][3] = exp2f(t[3]);
      }
    }

    // P -> Ps (wave-private rows); cvt_pk packed writes; fence-ordered
#pragma unroll
    for (int ni = 0; ni < 4; ++ni) {
      int q = wq + ni * 16 + lcol;
      int sw = q & 7;
#pragma unroll
      for (int mi = 0; mi < 4; ++mi) {
        uint2 pw;
        pw.x = cvtpk(sacc[mi][ni][0], sacc[mi][ni][1]);
        pw.y = cvtpk(sacc[mi][ni][2], sacc[mi][ni][3]);
        int j = 2 * mi + (quad >> 1);
        *(uint2*)(Ps + q * 64 + ((j ^ sw) * 8) + (quad & 1) * 4) = pw;
      }
    }
    lds_fence();

    sched_fence();
    ASM_VMCNT(4);                  // V(jt) landed; K(jt+1) still in flight (T4)
    __builtin_amdgcn_s_barrier();  // B1: all waves' V-loads visible
    sched_fence();

    // PV from Vt & Ps (+ ones-column row-sum into OaccL)
#pragma unroll
    for (int kk = 0; kk < 2; ++kk) {
      short8 pf[4];
#pragma unroll
      for (int mi = 0; mi < 4; ++mi) {
        int q = wq + mi * 16 + lcol;
        pf[mi] = *(const short8*)(Ps + q * 64 + (((kk * 4 + quad) ^ (q & 7)) * 8));
      }
#pragma unroll
      for (int nd = 0; nd < 4; ++nd) {
        int d = nd * 16 + lcol;
        short8 vf = *(const short8*)(Vt + d * 64 + (((kk * 4 + quad) ^ (d & 7)) * 8));
#pragma unroll
        for (int mi = 0; mi < 4; ++mi)
          Oacc[mi][nd] = __builtin_amdgcn_mfma_f32_16x16x32_bf16(pf[mi], vf, Oacc[mi][nd], 0, 0, 0);
      }
#pragma unroll
      for (int mi = 0; mi < 4; ++mi)
        OaccL[mi] = __builtin_amdgcn_mfma_f32_16x16x32_bf16(pf[mi], ones, OaccL[mi], 0, 0, 0);
    }
    lds_fence();
    __syncthreads();  // B2: K(jt+1) landed + all waves done with Vt/Ks[cur]
  }

  // epilogue: O/L -> bf16 into Ps (swizzled, wave-private rows), then coalesced store.
  // OaccL is already in C-row layout -> no shfl needed.
#pragma unroll
  for (int mi = 0; mi < 4; ++mi)
#pragma unroll
    for (int r = 0; r < 4; ++r) {
      float li = 1.f / OaccL[mi][r];
      int q = wq + mi * 16 + quad * 4 + r;
      int sw = q & 7;
#pragma unroll
      for (int nd = 0; nd < 4; ++nd) {
        int j = 2 * nd + (lcol >> 3);
        Ps[q * 64 + ((j ^ sw) * 8) + (lcol & 7)] = f2bf(Oacc[mi][nd][r] * li);
      }
    }
  __syncthreads();
#pragma unroll
  for (int i = 0; i < 8; ++i) {
    int c = tid + i * 128;
    int row = c >> 3, pj = c & 7;
    uint4 v = *(const uint4*)(Ps + row * 64 + ((pj ^ (row & 7)) * 8));
    *(uint4*)(Ctx + ((size_t)(b * 2048 + qt * 128 + row)) * 1024 + (hb & 15) * 64 + pj * 8) = v;
  }
}

// ---------------- launch ----------------
extern "C" void kernel_launch(void* const* d_in, const int* in_sizes, int n_in,
                              void* d_out, int out_size, void* d_ws, size_t ws_size,
                              hipStream_t stream) {
  const float* query = (const float*)d_in[0];
  const float* key_  = (const float*)d_in[1];
  const float* value = (const float*)d_in[2];
  const float* Wq = (const float*)d_in[3];
  const float* bq = (const float*)d_in[4];
  const float* Wk = (const float*)d_in[5];
  const float* bk = (const float*)d_in[6];
  const float* Wv = (const float*)d_in[7];
  const float* bv = (const float*)d_in[8];
  const float* Wo = (const float*)d_in[9];
  const float* bo = (const float*)d_in[10];

  char* w = (char*)d_ws;
  unsigned short* Wb  = (unsigned short*)w; w += (size_t)4 * 1024 * 1024 * 2;  // Wq,Wk,Wv,Wo bf16
  unsigned short* Qp  = (unsigned short*)w; w += (size_t)8192 * 1024 * 2;      // [B,H,S,64]
  unsigned short* Kp  = (unsigned short*)w; w += (size_t)8192 * 1024 * 2;      // [B,H,S,64]
  unsigned short* VTp = (unsigned short*)w; w += (size_t)8192 * 1024 * 2;      // [B,H,64,S]
  unsigned short* Ctx = (unsigned short*)w; w += (size_t)8192 * 1024 * 2;      // [B,S,1024]

  // bf16 activations: query/key park in d_out (32 MB, dead until gemm_o);
  // value parks in the Ctx slot (dead once qkv_gemm completes, before attn writes Ctx).
  unsigned short* XqB = (unsigned short*)d_out;
  unsigned short* XkB = (unsigned short*)d_out + (size_t)8192 * 1024;
  unsigned short* XvB = Ctx;

  cvt_all<<<28672, 256, 0, stream>>>(Wq, Wk, Wv, Wo, query, key_, value,
                                     Wb, XqB, XkB, XvB);

  qkv_gemm<<<dim3(8, 64, 3), 256, 0, stream>>>(XqB, XkB, XvB, Wb,
                                               bq, bk, bv, Qp, Kp, VTp);

  attn_kernel<<<dim3(16, 16, 4), 128, 0, stream>>>(Qp, Kp, VTp, Ctx);

  gemm_o<<<dim3(8, 64), 256, 0, stream>>>(Ctx, Wb + (size_t)3 * 1048576, bo, (float*)d_out);
}

// Round 5
// 375.601 us; speedup vs baseline: 1.0284x; 1.0284x over previous
//
#include <hip/hip_runtime.h>
#include <stdint.h>

typedef __attribute__((ext_vector_type(8))) short short8;     // 8 x bf16 MFMA operand
typedef __attribute__((ext_vector_type(4))) float floatx4;    // 16x16 MFMA accumulator
typedef __attribute__((ext_vector_type(16))) float floatx16;  // 32x32 MFMA accumulator

#define DEV __device__ __forceinline__

DEV unsigned short f2bf(float x) {  // fp32 -> bf16 RNE (epilogue-only)
  unsigned u = __float_as_uint(x);
  u += 0x7fffu + ((u >> 16) & 1u);
  return (unsigned short)(u >> 16);
}

// pack two fp32 -> two bf16 (round-half-up) in 3 VALU: 2 adds + v_perm
DEV unsigned pkbf(float hi, float lo) {
  return __builtin_amdgcn_perm(__float_as_uint(hi) + 0x8000u,
                               __float_as_uint(lo) + 0x8000u, 0x07060302u);
}

// single-instruction pack: dst = {lo16: bf16(a), hi16: bf16(b)} (RNE)
DEV unsigned cvtpk(float a, float b) {
  unsigned r;
  asm("v_cvt_pk_bf16_f32 %0, %1, %2" : "=v"(r) : "v"(a), "v"(b));
  return r;
}

DEV short8 pack4(unsigned a0, unsigned a1, unsigned b0, unsigned b1) {
  union { unsigned u[4]; short8 s; } t;
  t.u[0] = a0; t.u[1] = a1; t.u[2] = b0; t.u[3] = b1;
  return t.s;
}

DEV void load_lds16(const unsigned short* g, unsigned short* l) {
  __builtin_amdgcn_global_load_lds(
      (const __attribute__((address_space(1))) void*)g,
      (__attribute__((address_space(3))) void*)l, 16, 0, 0);
}

DEV void lds_fence() { asm volatile("" ::: "memory"); }

// counted vmcnt + raw barrier (T4): never drain to 0 mid-loop
#define ASM_VMCNT(n) asm volatile("s_waitcnt vmcnt(" #n ")" ::: "memory")
DEV void sched_fence() { __builtin_amdgcn_sched_barrier(0); }

// ---------------- one-shot fp32 -> bf16 of all 7 tensors ----------------
__global__ void cvt_all(const float* __restrict__ Wq, const float* __restrict__ Wk,
                        const float* __restrict__ Wv, const float* __restrict__ Wo,
                        const float* __restrict__ Xq, const float* __restrict__ Xk,
                        const float* __restrict__ Xv,
                        unsigned short* __restrict__ Wb, unsigned short* __restrict__ XqB,
                        unsigned short* __restrict__ XkB, unsigned short* __restrict__ XvB) {
  int bid = blockIdx.x;
  const float* src;
  unsigned short* dst;
  int off;
  if (bid < 4096) {
    int sel = bid >> 10;
    src = sel == 0 ? Wq : sel == 1 ? Wk : sel == 2 ? Wv : Wo;
    dst = Wb + (size_t)sel * 1048576;
    off = bid & 1023;
  } else {
    bid -= 4096;
    int sel = bid >> 13;
    src = sel == 0 ? Xq : sel == 1 ? Xk : Xv;
    dst = sel == 0 ? XqB : sel == 1 ? XkB : XvB;
    off = bid & 8191;
  }
  int i = (off * 256 + threadIdx.x) * 4;
  float4 v = *(const float4*)(src + i);
  uint2 o;
  o.x = pkbf(v.y, v.x);
  o.y = pkbf(v.w, v.z);
  *(uint2*)(dst + i) = o;
}

// ---------------- fused QKV projection (R3 swizzle restored), grid (8,64,3) ----------------
#define SCQ (0.125f * 1.44269504089f)
__global__ __launch_bounds__(256, 3) void qkv_gemm(
    const unsigned short* __restrict__ XqB, const unsigned short* __restrict__ XkB,
    const unsigned short* __restrict__ XvB,
    const unsigned short* __restrict__ Wb,
    const float* __restrict__ bq, const float* __restrict__ bk, const float* __restrict__ bv,
    unsigned short* __restrict__ Qp, unsigned short* __restrict__ Kp,
    unsigned short* __restrict__ VTp) {
  __shared__ alignas(16) unsigned short Xs[3][128 * 32];
  __shared__ alignas(16) unsigned short Ws[3][128 * 32];
  const int z = blockIdx.z;
  const unsigned short* X = z == 0 ? XqB : z == 1 ? XkB : XvB;
  const unsigned short* W = Wb + (size_t)z * 1048576;
  const float* bias = z == 0 ? bq : z == 1 ? bk : bv;

  const int tid = threadIdx.x;
  const int lane = tid & 63, wave = tid >> 6;
  const int lcol = lane & 15, quad = lane >> 4;
  // XCD L2-locality remap (R3): xcd owns a contiguous 8-block s-span
  const int n2 = blockIdx.x + 8 * blockIdx.y;
  const int xcd = n2 & 7, ii = n2 >> 3;
  const int wo = (ii >> 3) * 128;
  const int xo = (xcd * 8 + (ii & 7)) * 128;
  const int wm = (wave & 1) * 64;
  const int wn = (wave >> 1) * 64;

  floatx4 acc[4][4];
  for (int mi = 0; mi < 4; ++mi)
    for (int ni = 0; ni < 4; ++ni)
      for (int r = 0; r < 4; ++r) acc[mi][ni][r] = 0.f;

  auto stage = [&](int kt, int buf) {
    const int k0 = kt * 32;
    int c = tid;
    load_lds16(W + (size_t)(wo + (c >> 2)) * 1024 + k0 + (c & 3) * 8, Ws[buf] + c * 8);
    load_lds16(X + (size_t)(xo + (c >> 2)) * 1024 + k0 + (c & 3) * 8, Xs[buf] + c * 8);
    c = tid + 256;
    load_lds16(W + (size_t)(wo + (c >> 2)) * 1024 + k0 + (c & 3) * 8, Ws[buf] + c * 8);
    load_lds16(X + (size_t)(xo + (c >> 2)) * 1024 + k0 + (c & 3) * 8, Xs[buf] + c * 8);
  };

  stage(0, 0);
  stage(1, 1);
  int cur = 0;
  for (int kt = 0; kt < 32; ++kt) {
    sched_fence();
    ASM_VMCNT(4);
    __builtin_amdgcn_s_barrier();
    sched_fence();
    int nb = cur + 2; if (nb >= 3) nb -= 3;
    stage((kt + 2) & 31, nb);
    const unsigned short* Ab = (z < 2) ? Ws[cur] : Xs[cur];
    const unsigned short* Bb = (z < 2) ? Xs[cur] : Ws[cur];
    short8 af[4], bfr[4];
#pragma unroll
    for (int mi = 0; mi < 4; ++mi)
      af[mi] = *(const short8*)(Ab + (wm + mi * 16 + lcol) * 32 + quad * 8);
#pragma unroll
    for (int ni = 0; ni < 4; ++ni)
      bfr[ni] = *(const short8*)(Bb + (wn + ni * 16 + lcol) * 32 + quad * 8);
#pragma unroll
    for (int mi = 0; mi < 4; ++mi)
#pragma unroll
      for (int ni = 0; ni < 4; ++ni)
        acc[mi][ni] = __builtin_amdgcn_mfma_f32_16x16x32_bf16(af[mi], bfr[ni], acc[mi][ni], 0, 0, 0);
    cur = (cur == 2) ? 0 : cur + 1;
  }

  if (z < 2) {
    unsigned short* Out = z == 0 ? Qp : Kp;
    const float scl = z == 0 ? SCQ : 1.f;
#pragma unroll
    for (int mi = 0; mi < 4; ++mi) {
      int dbase = wo + wm + mi * 16 + quad * 4;
      float4 bv4 = *(const float4*)(bias + dbase);
      int h = dbase >> 6, dk = dbase & 63;
#pragma unroll
      for (int ni = 0; ni < 4; ++ni) {
        int sg = xo + wn + ni * 16 + lcol;
        int bb = sg >> 11, ss = sg & 2047;
        uint2 o;
        o.x = pkbf((acc[mi][ni][1] + bv4.y) * scl, (acc[mi][ni][0] + bv4.x) * scl);
        o.y = pkbf((acc[mi][ni][3] + bv4.w) * scl, (acc[mi][ni][2] + bv4.z) * scl);
        *(uint2*)(Out + ((size_t)(bb * 16 + h) * 2048 + ss) * 64 + dk) = o;
      }
    }
  } else {
#pragma unroll
    for (int ni = 0; ni < 4; ++ni) {
      int dg = wo + wn + ni * 16 + lcol;
      float bvx = bias[dg];
      int h = dg >> 6, dk = dg & 63;
#pragma unroll
      for (int mi = 0; mi < 4; ++mi) {
        int sbase = xo + wm + mi * 16 + quad * 4;
        int bb = sbase >> 11, ss = sbase & 2047;
        uint2 o;
        o.x = pkbf(acc[mi][ni][1] + bvx, acc[mi][ni][0] + bvx);
        o.y = pkbf(acc[mi][ni][3] + bvx, acc[mi][ni][2] + bvx);
        *(uint2*)(VTp + ((size_t)(bb * 16 + h) * 64 + dk) * 2048 + ss) = o;
      }
    }
  }
}

// ---------------- final O-projection: fp32 out, depth-2 counted-vmcnt ----------------
__global__ __launch_bounds__(256, 3) void gemm_o(
    const unsigned short* __restrict__ A, const unsigned short* __restrict__ Bw,
    const float* __restrict__ bias, float* __restrict__ Out) {
  __shared__ alignas(16) unsigned short Cs[3][128 * 32];
  __shared__ alignas(16) unsigned short Wos[3][128 * 32];
  const int tid = threadIdx.x;
  const int lane = tid & 63, wave = tid >> 6;
  const int lcol = lane & 15, quad = lane >> 4;
  const int n2 = blockIdx.x + 8 * blockIdx.y;
  const int xcd = n2 & 7, ii = n2 >> 3;
  const int co = (ii >> 3) * 128;
  const int so = (xcd * 8 + (ii & 7)) * 128;
  const int wm = (wave & 1) * 64;
  const int wn = (wave >> 1) * 64;

  floatx4 acc[4][4];
  for (int mi = 0; mi < 4; ++mi)
    for (int ni = 0; ni < 4; ++ni)
      for (int r = 0; r < 4; ++r) acc[mi][ni][r] = 0.f;

  auto stage = [&](int kt, int buf) {
    const int k0 = kt * 32;
    int c = tid;
    load_lds16(Bw + (size_t)(co + (c >> 2)) * 1024 + k0 + (c & 3) * 8, Wos[buf] + c * 8);
    load_lds16(A  + (size_t)(so + (c >> 2)) * 1024 + k0 + (c & 3) * 8, Cs[buf] + c * 8);
    c = tid + 256;
    load_lds16(Bw + (size_t)(co + (c >> 2)) * 1024 + k0 + (c & 3) * 8, Wos[buf] + c * 8);
    load_lds16(A  + (size_t)(so + (c >> 2)) * 1024 + k0 + (c & 3) * 8, Cs[buf] + c * 8);
  };

  stage(0, 0);
  stage(1, 1);
  int cur = 0;
  for (int kt = 0; kt < 32; ++kt) {
    sched_fence();
    ASM_VMCNT(4);
    __builtin_amdgcn_s_barrier();
    sched_fence();
    int nb = cur + 2; if (nb >= 3) nb -= 3;
    stage((kt + 2) & 31, nb);
    short8 af[4], bfr[4];
#pragma unroll
    for (int mi = 0; mi < 4; ++mi)
      af[mi] = *(const short8*)(Wos[cur] + (wm + mi * 16 + lcol) * 32 + quad * 8);
#pragma unroll
    for (int ni = 0; ni < 4; ++ni)
      bfr[ni] = *(const short8*)(Cs[cur] + (wn + ni * 16 + lcol) * 32 + quad * 8);
#pragma unroll
    for (int mi = 0; mi < 4; ++mi)
#pragma unroll
      for (int ni = 0; ni < 4; ++ni)
        acc[mi][ni] = __builtin_amdgcn_mfma_f32_16x16x32_bf16(af[mi], bfr[ni], acc[mi][ni], 0, 0, 0);
    cur = (cur == 2) ? 0 : cur + 1;
  }
#pragma unroll
  for (int mi = 0; mi < 4; ++mi) {
    int cb = co + wm + mi * 16 + quad * 4;
    float4 bv4 = *(const float4*)(bias + cb);
#pragma unroll
    for (int ni = 0; ni < 4; ++ni) {
      int sg = so + wn + ni * 16 + lcol;
      float4 o;
      o.x = acc[mi][ni][0] + bv4.x;
      o.y = acc[mi][ni][1] + bv4.y;
      o.z = acc[mi][ni][2] + bv4.z;
      o.w = acc[mi][ni][3] + bv4.w;
      *(float4*)(Out + (size_t)sg * 1024 + cb) = o;
    }
  }
}

// ---------------- flash attention, 32x32 MFMA, in-register P ----------------
// One block = (b,h,128 q rows); 4 waves x 32q. S^T via mfma_32x32x16(K,Q): q = lane&31 is
// lane-local for softmax AND for the PV A-operand. P redistributed across half-lanes by
// v_permlane32_swap (2 per kk) -- NO P LDS round-trip, no fences. L via ones-column MFMA
// (C-row domain == O rows -> lane-local epilogue). K/V triple-buffered, 1 barrier/jt with
// counted vmcnt(4).
__global__ __launch_bounds__(256, 3) void attn_kernel(
    const unsigned short* __restrict__ Qp, const unsigned short* __restrict__ Kp,
    const unsigned short* __restrict__ VTp, unsigned short* __restrict__ Ctx) {
  __shared__ alignas(16) unsigned short Ks[3][64 * 64];  // K tiles (24KB); reused as O-stage
  __shared__ alignas(16) unsigned short Vt[3][64 * 64];  // V^T tiles (24KB)

  const int tid = threadIdx.x;
  const int lane = tid & 63, wave = tid >> 6;
  const int l31 = lane & 31, hh = lane >> 5;
  const int wq = wave * 32;
  // XCD L2-locality remap (R3): xcd owns 8 (b,h) pairs
  const int n = blockIdx.x + 16 * (blockIdx.y + 16 * blockIdx.z);
  const int xcd = n & 7, ii = n >> 3;
  const int hb = xcd * 8 + (ii & 7);  // = b*16 + h
  const int qt = ii >> 3;
  const size_t bh = (size_t)hb * 2048 * 64;
  const int b = hb >> 4;
  const unsigned short* Qb = Qp + bh + (size_t)qt * 128 * 64;
  const unsigned short* Kb = Kp + bh;
  const unsigned short* VTb = VTp + bh;

  // Q fragments straight from global: qf[st] = Q[wq+l31][16*st + 8*hh + j]
  short8 qf[4];
#pragma unroll
  for (int st = 0; st < 4; ++st)
    qf[st] = *(const short8*)(Qb + (wq + l31) * 64 + st * 16 + hh * 8);

  auto stageK = [&](int jt, int buf) {
#pragma unroll
    for (int i = 0; i < 2; ++i) {
      int p = tid + i * 256;
      int kr = p >> 3, kj = p & 7;
      load_lds16(Kb + (size_t)jt * 4096 + kr * 64 + ((kj ^ (kr & 7)) * 8), Ks[buf] + p * 8);
    }
  };
  auto stageV = [&](int jt, int buf) {
#pragma unroll
    for (int i = 0; i < 2; ++i) {
      int p = tid + i * 256;
      int vr = p >> 3, vj = p & 7;
      load_lds16(VTb + (size_t)vr * 2048 + jt * 64 + ((vj ^ (vr & 7)) * 8), Vt[buf] + p * 8);
    }
  };

  stageK(0, 0); stageV(0, 0);
  stageK(1, 1); stageV(1, 1);
  __syncthreads();  // tiles 0,1 resident

  short8 ones;
#pragma unroll
  for (int j = 0; j < 8; ++j) ones[j] = (short)0x3f80;

  float M = -1e30f;  // per-lane: q = wq + l31 (identical in both halves)
  floatx16 Oacc[2], OaccL;
#pragma unroll
  for (int r = 0; r < 16; ++r) { Oacc[0][r] = 0.f; Oacc[1][r] = 0.f; OaccL[r] = 0.f; }

  int cur = 0;
  for (int jt = 0; jt < 32; ++jt) {
    int nb = cur + 2; if (nb >= 3) nb -= 3;
    const int jn = (jt + 2) & 31;  // wrap-issue keeps vmcnt uniform (epilogue drains)
    stageK(jn, nb);
    stageV(jn, nb);

    // S^T[k=64][q=32]: 2 mk-blocks x 4 d-steps of 32x32x16
    const unsigned short* Kc = Ks[cur];
    floatx16 sacc[2];
#pragma unroll
    for (int r = 0; r < 16; ++r) { sacc[0][r] = 0.f; sacc[1][r] = 0.f; }
#pragma unroll
    for (int st = 0; st < 4; ++st)
#pragma unroll
      for (int mk = 0; mk < 2; ++mk) {
        int row = mk * 32 + l31;
        short8 kf = *(const short8*)(Kc + row * 64 + (((2 * st + hh) ^ (row & 7)) * 8));
        sacc[mk] = __builtin_amdgcn_mfma_f32_32x32x16_bf16(kf, qf[st], sacc[mk], 0, 0, 0);
      }

    // lane-local row max (lane holds 32 of 64 k for its q; other half in lane^32)
    float t8[8];
#pragma unroll
    for (int r = 0; r < 8; ++r)
      t8[r] = fmaxf(fmaxf(sacc[0][r], sacc[0][r + 8]), fmaxf(sacc[1][r], sacc[1][r + 8]));
    float t4a = fmaxf(t8[0], t8[4]), t4b = fmaxf(t8[1], t8[5]);
    float t4c = fmaxf(t8[2], t8[6]), t4d = fmaxf(t8[3], t8[7]);
    float mloc = fmaxf(fmaxf(t4a, t4b), fmaxf(t4c, t4d));
    float m2 = fmaxf(mloc, __shfl_xor(mloc, 32));

    const int skip = __all(m2 <= M + 8.f);
    if (!skip) {
      float mnew = fmaxf(M, m2);
      float alpha = exp2f(M - mnew);
      M = mnew;
      // O rows are q_r = (r&3)+8*(r>>2)+4*hh; fetch that q's alpha cross-lane (rare path)
#pragma unroll
      for (int r = 0; r < 16; ++r) {
        int srcl = (r & 3) + 8 * (r >> 2) + hh * 4;
        float ar = __shfl(alpha, srcl);
        Oacc[0][r] *= ar;
        Oacc[1][r] *= ar;
        OaccL[r] *= ar;
      }
    }
    // exp (base-2 logits; Q pre-scaled)
#pragma unroll
    for (int mk = 0; mk < 2; ++mk)
#pragma unroll
      for (int r = 0; r < 16; ++r) sacc[mk][r] = exp2f(sacc[mk][r] - M);

    // pack P to bf16: w[mk][c] covers k = 8c + 4hh + 32mk + {0..3}
    unsigned wpk[2][4][2];
#pragma unroll
    for (int mk = 0; mk < 2; ++mk)
#pragma unroll
      for (int c = 0; c < 4; ++c) {
        wpk[mk][c][0] = cvtpk(sacc[mk][4 * c + 0], sacc[mk][4 * c + 1]);
        wpk[mk][c][1] = cvtpk(sacc[mk][4 * c + 2], sacc[mk][4 * c + 3]);
      }

    // PV: per kk (k-16-block), redistribute halves via permlane32_swap, then 2 nd MFMAs + L
    const unsigned short* Vc = Vt[cur];
#pragma unroll
    for (int kk = 0; kk < 4; ++kk) {
      const int e = kk & 1, mk = kk >> 1;
      unsigned a0 = wpk[mk][2 * e][0], b0 = wpk[mk][2 * e + 1][0];
      unsigned a1 = wpk[mk][2 * e][1], b1 = wpk[mk][2 * e + 1][1];
      asm("v_permlane32_swap_b32 %0, %1" : "+v"(a0), "+v"(b0));
      asm("v_permlane32_swap_b32 %0, %1" : "+v"(a1), "+v"(b1));
      short8 pa = pack4(a0, a1, b0, b1);  // A[m=q=l31][kc=8hh+j], k = 16kk + kc
#pragma unroll
      for (int nd = 0; nd < 2; ++nd) {
        int row = nd * 32 + l31;
        short8 vf = *(const short8*)(Vc + row * 64 + (((2 * kk + hh) ^ (row & 7)) * 8));
        Oacc[nd] = __builtin_amdgcn_mfma_f32_32x32x16_bf16(pa, vf, Oacc[nd], 0, 0, 0);
      }
      OaccL = __builtin_amdgcn_mfma_f32_32x32x16_bf16(pa, ones, OaccL, 0, 0, 0);
    }

    sched_fence();
    ASM_VMCNT(4);                  // tile jt+1 landed; jt+2 still in flight
    __builtin_amdgcn_s_barrier();
    sched_fence();
    cur = (cur == 2) ? 0 : cur + 1;
  }

  // epilogue: drain wrap-staged stragglers (they land in Ks[*] which we reuse as O-stage)
  ASM_VMCNT(0);
  __syncthreads();
  unsigned short* Obuf = &Ks[0][0];  // 128x64 bf16 = 16KB (Ks[0..1])
  float linv[16];
#pragma unroll
  for (int r = 0; r < 16; ++r) linv[r] = 1.f / OaccL[r];
#pragma unroll
  for (int nd = 0; nd < 2; ++nd)
#pragma unroll
    for (int r = 0; r < 16; ++r) {
      int q = wq + (r & 3) + 8 * (r >> 2) + hh * 4;
      int d = nd * 32 + l31;
      Obuf[q * 64 + (((d >> 3) ^ (q & 7)) * 8) + (d & 7)] = f2bf(Oacc[nd][r] * linv[r]);
    }
  __syncthreads();
#pragma unroll
  for (int i = 0; i < 4; ++i) {
    int c = tid + i * 256;
    int row = c >> 3, pj = c & 7;
    uint4 v = *(const uint4*)(Obuf + row * 64 + ((pj ^ (row & 7)) * 8));
    *(uint4*)(Ctx + ((size_t)(b * 2048 + qt * 128 + row)) * 1024 + (hb & 15) * 64 + pj * 8) = v;
  }
}

// ---------------- launch ----------------
extern "C" void kernel_launch(void* const* d_in, const int* in_sizes, int n_in,
                              void* d_out, int out_size, void* d_ws, size_t ws_size,
                              hipStream_t stream) {
  const float* query = (const float*)d_in[0];
  const float* key_  = (const float*)d_in[1];
  const float* value = (const float*)d_in[2];
  const float* Wq = (const float*)d_in[3];
  const float* bq = (const float*)d_in[4];
  const float* Wk = (const float*)d_in[5];
  const float* bk = (const float*)d_in[6];
  const float* Wv = (const float*)d_in[7];
  const float* bv = (const float*)d_in[8];
  const float* Wo = (const float*)d_in[9];
  const float* bo = (const float*)d_in[10];

  char* w = (char*)d_ws;
  unsigned short* Wb  = (unsigned short*)w; w += (size_t)4 * 1024 * 1024 * 2;  // Wq,Wk,Wv,Wo bf16
  unsigned short* Qp  = (unsigned short*)w; w += (size_t)8192 * 1024 * 2;      // [B,H,S,64]
  unsigned short* Kp  = (unsigned short*)w; w += (size_t)8192 * 1024 * 2;      // [B,H,S,64]
  unsigned short* VTp = (unsigned short*)w; w += (size_t)8192 * 1024 * 2;      // [B,H,64,S]
  unsigned short* Ctx = (unsigned short*)w; w += (size_t)8192 * 1024 * 2;      // [B,S,1024]

  unsigned short* XqB = (unsigned short*)d_out;
  unsigned short* XkB = (unsigned short*)d_out + (size_t)8192 * 1024;
  unsigned short* XvB = Ctx;

  cvt_all<<<28672, 256, 0, stream>>>(Wq, Wk, Wv, Wo, query, key_, value,
                                     Wb, XqB, XkB, XvB);

  qkv_gemm<<<dim3(8, 64, 3), 256, 0, stream>>>(XqB, XkB, XvB, Wb,
                                               bq, bk, bv, Qp, Kp, VTp);

  attn_kernel<<<dim3(16, 16, 4), 256, 0, stream>>>(Qp, Kp, VTp, Ctx);

  gemm_o<<<dim3(8, 64), 256, 0, stream>>>(Ctx, Wb + (size_t)3 * 1048576, bo, (float*)d_out);
}